// Round 2
// baseline (419.255 us; speedup 1.0000x reference)
//
#include <hip/hip_runtime.h>
#include <hip/hip_bf16.h>

typedef unsigned short u16;
typedef __attribute__((ext_vector_type(8))) short short8;   // 8 bf16 = 4 VGPR (MFMA A/B frag)
typedef __attribute__((ext_vector_type(4))) float floatx4;  // MFMA C/D frag

static __device__ __forceinline__ u16 f2bf(float x) {
    __hip_bfloat16 h = __float2bfloat16(x);
    union { __hip_bfloat16 h; u16 u; } cv; cv.h = h; return cv.u;
}
static __device__ __forceinline__ float bf2f(u16 u) {
    union { u16 u; __hip_bfloat16 h; } cv; cv.u = u;
    return __bfloat162float(cv.h);
}

// ---------------- elementwise fp32 -> bf16 convert (feats) ----------------
__global__ void k_cvt(const float* __restrict__ in, u16* __restrict__ out) {
    int i = (blockIdx.x * 256 + threadIdx.x) * 4;
    float4 v = *(const float4*)&in[i];
    out[i + 0] = f2bf(v.x); out[i + 1] = f2bf(v.y);
    out[i + 2] = f2bf(v.z); out[i + 3] = f2bf(v.w);
}

// ---------- tiled transpose fp32[R][C] -> bf16[C][R] (weight prep) ----------
__global__ void k_transpose(const float* __restrict__ in, u16* __restrict__ out,
                            int R, int Cn) {
    __shared__ float t[64][65];
    int c  = threadIdx.x & 63;
    int r0 = threadIdx.x >> 6;
    int bx = blockIdx.x, by = blockIdx.y;
    for (int rr = r0; rr < 64; rr += 4)
        t[rr][c] = in[(long)(by * 64 + rr) * Cn + bx * 64 + c];
    __syncthreads();
    for (int rr = r0; rr < 64; rr += 4)
        out[(long)(bx * 64 + rr) * R + by * 64 + c] = f2bf(t[c][rr]);
}

// ---------------- q/k projections from fpjT[b,hd,n] ----------------
__global__ void k_qk(const u16* __restrict__ fpjT,
                     const float* __restrict__ qw, const float* __restrict__ kw,
                     const float* __restrict__ qb, const float* __restrict__ kb,
                     float* __restrict__ qo, float* __restrict__ ko) {
    int bh = blockIdx.y;
    int n  = blockIdx.x * 256 + threadIdx.x;
    __shared__ float wq[256], wk[256];
    wq[threadIdx.x] = qw[threadIdx.x];
    wk[threadIdx.x] = kw[threadIdx.x];
    __syncthreads();
    const u16* base = fpjT + ((long)bh << 18) + n;
    float qa = 0.f, ka = 0.f;
    for (int d = 0; d < 256; d++) {
        float v = bf2f(base[(long)d << 10]);         // coalesced over n
        qa += v * wq[d]; ka += v * wk[d];
    }
    qo[(bh << 10) + n] = qa + qb[0];
    ko[(bh << 10) + n] = ka + kb[0];
}

// ---------------- templated NT bf16 GEMM: C = A[M][K] * Bt[N][K]^T -----------
// 4 waves as 2x2; per-wave frag grid WM x WN of 16x16x32 MFMA.
// LDS rows padded to 40 elems (80 B).
// EPI 1 (G1): rows = hd (M=2048), cols = global n (N=8192).
//   store bf16 fpjT[(b*2048+hd)*1024 + nn] + fc_b[hd]; coalesced in nn.
// EPI 3 (G3): fp32 sigmoid(acc + bias[col] + resid) store, ldc = 256.
template <int EPI, int BM, int BN, int WM, int WN>
__global__ __launch_bounds__(256, 2)
void gemm_nt(const u16* __restrict__ A, const u16* __restrict__ Bt,
             int lda, int ldb, int K,
             void* __restrict__ Cv,
             const float* __restrict__ bias,
             const float* __restrict__ resid) {
    __shared__ u16 As[BM * 40];
    __shared__ u16 Bs[BN * 40];
    int rowBase = blockIdx.y * BM;
    int colBase = blockIdx.x * BN;
    int tid  = threadIdx.x;
    int wave = tid >> 6, lane = tid & 63;
    int wr = wave >> 1, wc = wave & 1;
    int q  = lane >> 4, n16 = lane & 15;

    floatx4 acc[WM][WN] = {};

    int sm = tid >> 2;          // 0..63 staging row
    int sk = (tid & 3) * 8;     // k-chunk within BK=32

    for (int k0 = 0; k0 < K; k0 += 32) {
        int4 al[BM / 64], bl[BN / 64];
        #pragma unroll
        for (int r = 0; r < BM / 64; r++)
            al[r] = *(const int4*)&A[(long)(rowBase + sm + 64 * r) * lda + k0 + sk];
        #pragma unroll
        for (int r = 0; r < BN / 64; r++)
            bl[r] = *(const int4*)&Bt[(long)(colBase + sm + 64 * r) * ldb + k0 + sk];
        __syncthreads();   // previous iter's frag reads done
        #pragma unroll
        for (int r = 0; r < BM / 64; r++)
            *(int4*)&As[(sm + 64 * r) * 40 + sk] = al[r];
        #pragma unroll
        for (int r = 0; r < BN / 64; r++)
            *(int4*)&Bs[(sm + 64 * r) * 40 + sk] = bl[r];
        __syncthreads();
        short8 af[WM], bfr[WN];
        #pragma unroll
        for (int i = 0; i < WM; i++)
            af[i] = *(short8*)&As[(wr * WM * 16 + i * 16 + n16) * 40 + q * 8];
        #pragma unroll
        for (int i = 0; i < WN; i++)
            bfr[i] = *(short8*)&Bs[(wc * WN * 16 + i * 16 + n16) * 40 + q * 8];
        #pragma unroll
        for (int mi = 0; mi < WM; mi++)
            #pragma unroll
            for (int ni = 0; ni < WN; ni++)
                acc[mi][ni] = __builtin_amdgcn_mfma_f32_16x16x32_bf16(
                    af[mi], bfr[ni], acc[mi][ni], 0, 0, 0);
    }

    u16*   Cb = (u16*)Cv;
    float* Cf = (float*)Cv;
    #pragma unroll
    for (int mi = 0; mi < WM; mi++) {
        #pragma unroll
        for (int r = 0; r < 4; r++) {
            int grow = rowBase + wr * WM * 16 + mi * 16 + q * 4 + r;
            #pragma unroll
            for (int ni = 0; ni < WN; ni++) {
                int gcol = colBase + wc * WN * 16 + ni * 16 + n16;
                float v = acc[mi][ni][r];
                if (EPI == 1) {
                    v += bias[grow];                   // bias over hd rows
                    int b = gcol >> 10, nn = gcol & 1023;
                    Cb[(((long)(b * 2048 + grow)) << 10) + nn] = f2bf(v);
                } else {
                    v += bias[gcol] + resid[(long)grow * 256 + gcol];
                    Cf[(long)grow * 256 + gcol] = 1.f / (1.f + __expf(-v));
                }
            }
        }
    }
}

// -------- fused attention: out_h = softmax(adj*exp(leaky(q+k))) @ V --------
// One block = 64 query rows x all 256 d-cols for one (b,h). P-tile generated
// in LDS (bf16) on the fly; row-sums accumulated in registers; scaled 1/l at
// epilogue. P is never materialized to HBM.
__global__ __launch_bounds__(256, 2)
void k_attn(const float* __restrict__ adj, const float* __restrict__ qv,
            const float* __restrict__ kv, const u16* __restrict__ fpjT,
            u16* __restrict__ outh) {
    __shared__ u16 As[64 * 40];           // P-tile 64 x 32
    __shared__ u16 Bs[256 * 40];          // V^T tile 256(d) x 32(j)
    __shared__ float qS[64], kS[1024], lsumS[256], rlS[64];

    int z = blockIdx.y;                   // bh
    int b = z >> 3, h = z & 7;
    int i0 = blockIdx.x * 64;
    int tid = threadIdx.x;
    int wave = tid >> 6, lane = tid & 63;
    int wr = wave >> 1, wc = wave & 1;
    int q  = lane >> 4, n16 = lane & 15;

    *(float4*)&kS[tid * 4] = *(const float4*)&kv[(z << 10) + tid * 4];
    if (tid < 64) qS[tid] = qv[(z << 10) + i0 + tid];
    __syncthreads();

    floatx4 acc[2][8] = {};
    int sm = tid >> 2;                    // V staging row
    int sk = (tid & 3) * 8;
    int ar = tid >> 2;                    // P row (0..63)
    int jq = (tid & 3) * 8;               // P j-offset within BK
    const float* adjRow = adj + ((long)b << 20) + ((long)(i0 + ar) << 10) + jq;
    const u16* Vbase = fpjT + ((long)z << 18);
    float lsum = 0.f;

    for (int k0 = 0; k0 < 1024; k0 += 32) {
        int4 bl[4];
        #pragma unroll
        for (int r = 0; r < 4; r++)
            bl[r] = *(const int4*)&Vbase[(long)(sm + 64 * r) * 1024 + k0 + sk];
        float4 a0 = *(const float4*)&adjRow[k0];
        float4 a1 = *(const float4*)&adjRow[k0 + 4];
        float av[8] = {a0.x, a0.y, a0.z, a0.w, a1.x, a1.y, a1.z, a1.w};
        float qi = qS[ar];
        short8 pv;
        #pragma unroll
        for (int e = 0; e < 8; e++) {
            float s = qi + kS[k0 + jq + e];
            s = s > 0.f ? s : 0.01f * s;             // leaky_relu
            float p = av[e] > 0.f ? __expf(s) : 0.f;
            lsum += p;
            pv[e] = (short)f2bf(p);
        }
        __syncthreads();   // previous iter's frag reads done
        *(short8*)&As[ar * 40 + jq] = pv;
        #pragma unroll
        for (int r = 0; r < 4; r++)
            *(int4*)&Bs[(sm + 64 * r) * 40 + sk] = bl[r];
        __syncthreads();
        short8 af[2], bfr[8];
        #pragma unroll
        for (int i = 0; i < 2; i++)
            af[i] = *(short8*)&As[(wr * 32 + i * 16 + n16) * 40 + q * 8];
        #pragma unroll
        for (int i = 0; i < 8; i++)
            bfr[i] = *(short8*)&Bs[(wc * 128 + i * 16 + n16) * 40 + q * 8];
        #pragma unroll
        for (int mi = 0; mi < 2; mi++)
            #pragma unroll
            for (int ni = 0; ni < 8; ni++)
                acc[mi][ni] = __builtin_amdgcn_mfma_f32_16x16x32_bf16(
                    af[mi], bfr[ni], acc[mi][ni], 0, 0, 0);
    }

    // row-sum reduction: 4 threads per row
    lsumS[tid] = lsum;
    __syncthreads();
    if (tid < 64) {
        float l = lsumS[4 * tid] + lsumS[4 * tid + 1] +
                  lsumS[4 * tid + 2] + lsumS[4 * tid + 3];
        rlS[tid] = l > 0.f ? 1.f / l : 0.f;
    }
    __syncthreads();

    #pragma unroll
    for (int mi = 0; mi < 2; mi++) {
        #pragma unroll
        for (int r = 0; r < 4; r++) {
            int grow = wr * 32 + mi * 16 + q * 4 + r;
            float s = rlS[grow];
            long base = (long)(b * 1024 + i0 + grow) * 2048 + h * 256;
            #pragma unroll
            for (int ni = 0; ni < 8; ni++) {
                int gcol = wc * 128 + ni * 16 + n16;
                outh[base + gcol] = f2bf(acc[mi][ni][r] * s);
            }
        }
    }
}

extern "C" void kernel_launch(void* const* d_in, const int* in_sizes, int n_in,
                              void* d_out, int out_size, void* d_ws, size_t ws_size,
                              hipStream_t stream) {
    const float* feats = (const float*)d_in[0];
    const float* adj   = (const float*)d_in[1];
    const float* fc_w  = (const float*)d_in[2];
    const float* fc_b  = (const float*)d_in[3];
    const float* q_w   = (const float*)d_in[4];
    const float* q_b   = (const float*)d_in[5];
    const float* k_w   = (const float*)d_in[6];
    const float* k_b   = (const float*)d_in[7];
    const float* fp_w  = (const float*)d_in[8];
    const float* fp_b  = (const float*)d_in[9];

    char* ws = (char*)d_ws;
    u16*   featsB = (u16*)ws;   ws += (size_t)2097152 * 2;   // [8192][256] bf16
    u16*   fcwT   = (u16*)ws;   ws += (size_t)524288 * 2;    // [2048][256] bf16
    u16*   fpwT   = (u16*)ws;   ws += (size_t)524288 * 2;    // [256][2048] bf16
    u16*   fpjT   = (u16*)ws;   ws += (size_t)16777216 * 2;  // [b,hd,n] bf16
    float* qv     = (float*)ws; ws += (size_t)65536 * 4;     // [b,h,n]
    float* kv     = (float*)ws; ws += (size_t)65536 * 4;
    u16*   outh   = (u16*)ws;   ws += (size_t)16777216 * 2;  // [(b,n)][(h,d)] bf16

    // setup: conversions + weight transposes
    k_cvt<<<2048, 256, 0, stream>>>(feats, featsB);
    k_transpose<<<dim3(32, 4), 256, 0, stream>>>(fc_w, fcwT, 256, 2048);
    k_transpose<<<dim3(4, 32), 256, 0, stream>>>(fp_w, fpwT, 2048, 256);

    // G1 (swapped orientation): fpjT[hd][n] = fc_w^T @ feats^T, coalesced store
    gemm_nt<1, 128, 128, 4, 4><<<dim3(64, 16), 256, 0, stream>>>(
        fcwT, featsB, 256, 256, 256, (void*)fpjT, fc_b, nullptr);

    // q, k
    k_qk<<<dim3(4, 64), 256, 0, stream>>>(fpjT, q_w, k_w, q_b, k_b, qv, kv);

    // fused scores + P@V + 1/l scaling
    k_attn<<<dim3(16, 64), 256, 0, stream>>>(adj, qv, kv, fpjT, outh);

    // G3: sigmoid(outh @ fp_w + fp_b + feats), 64x64 tiles -> 512 blocks
    gemm_nt<3, 64, 64, 2, 2><<<dim3(4, 128), 256, 0, stream>>>(
        outh, fpwT, 2048, 2048, 2048, d_out, fp_b, feats);
}

// Round 3
// 376.949 us; speedup vs baseline: 1.1122x; 1.1122x over previous
//
#include <hip/hip_runtime.h>
#include <hip/hip_bf16.h>

typedef unsigned short u16;
typedef unsigned int u32;
typedef unsigned long long u64;
typedef __attribute__((ext_vector_type(8))) short short8;   // 8 bf16 = 4 VGPR (MFMA A/B frag)
typedef __attribute__((ext_vector_type(4))) float floatx4;  // MFMA C/D frag

static __device__ __forceinline__ u16 f2bf(float x) {
    __hip_bfloat16 h = __float2bfloat16(x);
    union { __hip_bfloat16 h; u16 u; } cv; cv.h = h; return cv.u;
}
static __device__ __forceinline__ float bf2f(u16 u) {
    union { u16 u; __hip_bfloat16 h; } cv; cv.u = u;
    return __bfloat162float(cv.h);
}

// ---------------- elementwise fp32 -> bf16 convert (feats) ----------------
__global__ void k_cvt(const float* __restrict__ in, u16* __restrict__ out) {
    int i = (blockIdx.x * 256 + threadIdx.x) * 4;
    float4 v = *(const float4*)&in[i];
    out[i + 0] = f2bf(v.x); out[i + 1] = f2bf(v.y);
    out[i + 2] = f2bf(v.z); out[i + 3] = f2bf(v.w);
}

// ---------------- adj fp32 -> bitmask (1 bit per entry, wave ballot) --------
// m[w64] covers 64 consecutive cols; u32 view: word j>>5, bit j&31.
__global__ void k_mask(const float* __restrict__ adj, u64* __restrict__ m) {
    long i = (long)blockIdx.x * 256 + threadIdx.x;
    float v = adj[i];
    u64 bm = __ballot(v > 0.f);
    if ((threadIdx.x & 63) == 0) m[i >> 6] = bm;
}

// ---------- tiled transpose fp32[R][C] -> bf16[C][R] (weight prep) ----------
__global__ void k_transpose(const float* __restrict__ in, u16* __restrict__ out,
                            int R, int Cn) {
    __shared__ float t[64][65];
    int c  = threadIdx.x & 63;
    int r0 = threadIdx.x >> 6;
    int bx = blockIdx.x, by = blockIdx.y;
    for (int rr = r0; rr < 64; rr += 4)
        t[rr][c] = in[(long)(by * 64 + rr) * Cn + bx * 64 + c];
    __syncthreads();
    for (int rr = r0; rr < 64; rr += 4)
        out[(long)(bx * 64 + rr) * R + by * 64 + c] = f2bf(t[c][rr]);
}

// ---------------- q/k projections from fpjT[b,hd,n] ----------------
__global__ void k_qk(const u16* __restrict__ fpjT,
                     const float* __restrict__ qw, const float* __restrict__ kw,
                     const float* __restrict__ qb, const float* __restrict__ kb,
                     float* __restrict__ qo, float* __restrict__ ko) {
    int bh = blockIdx.y;
    int n  = blockIdx.x * 256 + threadIdx.x;
    __shared__ float wq[256], wk[256];
    wq[threadIdx.x] = qw[threadIdx.x];
    wk[threadIdx.x] = kw[threadIdx.x];
    __syncthreads();
    const u16* base = fpjT + ((long)bh << 18) + n;
    float qa = 0.f, ka = 0.f;
    for (int d = 0; d < 256; d++) {
        float v = bf2f(base[(long)d << 10]);         // coalesced over n
        qa += v * wq[d]; ka += v * wk[d];
    }
    qo[(bh << 10) + n] = qa + qb[0];
    ko[(bh << 10) + n] = ka + kb[0];
}

// ---------------- templated NT bf16 GEMM: C = A[M][K] * Bt[N][K]^T -----------
// 4 waves as 2x2; per-wave frag grid WM x WN of 16x16x32 MFMA.
// LDS rows padded to 40 elems (80 B).
// EPI 1 (G1): rows = hd (M=2048), cols = global n (N=8192).
//   store bf16 fpjT[(b*2048+hd)*1024 + nn] + fc_b[hd]; coalesced in nn.
// EPI 3 (G3): fp32 sigmoid(acc + bias[col] + resid) store, ldc = 256.
template <int EPI, int BM, int BN, int WM, int WN>
__global__ __launch_bounds__(256, 2)
void gemm_nt(const u16* __restrict__ A, const u16* __restrict__ Bt,
             int lda, int ldb, int K,
             void* __restrict__ Cv,
             const float* __restrict__ bias,
             const float* __restrict__ resid) {
    __shared__ u16 As[BM * 40];
    __shared__ u16 Bs[BN * 40];
    int rowBase = blockIdx.y * BM;
    int colBase = blockIdx.x * BN;
    int tid  = threadIdx.x;
    int wave = tid >> 6, lane = tid & 63;
    int wr = wave >> 1, wc = wave & 1;
    int q  = lane >> 4, n16 = lane & 15;

    floatx4 acc[WM][WN] = {};

    int sm = tid >> 2;          // 0..63 staging row
    int sk = (tid & 3) * 8;     // k-chunk within BK=32

    for (int k0 = 0; k0 < K; k0 += 32) {
        int4 al[BM / 64], bl[BN / 64];
        #pragma unroll
        for (int r = 0; r < BM / 64; r++)
            al[r] = *(const int4*)&A[(long)(rowBase + sm + 64 * r) * lda + k0 + sk];
        #pragma unroll
        for (int r = 0; r < BN / 64; r++)
            bl[r] = *(const int4*)&Bt[(long)(colBase + sm + 64 * r) * ldb + k0 + sk];
        __syncthreads();   // previous iter's frag reads done
        #pragma unroll
        for (int r = 0; r < BM / 64; r++)
            *(int4*)&As[(sm + 64 * r) * 40 + sk] = al[r];
        #pragma unroll
        for (int r = 0; r < BN / 64; r++)
            *(int4*)&Bs[(sm + 64 * r) * 40 + sk] = bl[r];
        __syncthreads();
        short8 af[WM], bfr[WN];
        #pragma unroll
        for (int i = 0; i < WM; i++)
            af[i] = *(short8*)&As[(wr * WM * 16 + i * 16 + n16) * 40 + q * 8];
        #pragma unroll
        for (int i = 0; i < WN; i++)
            bfr[i] = *(short8*)&Bs[(wc * WN * 16 + i * 16 + n16) * 40 + q * 8];
        #pragma unroll
        for (int mi = 0; mi < WM; mi++)
            #pragma unroll
            for (int ni = 0; ni < WN; ni++)
                acc[mi][ni] = __builtin_amdgcn_mfma_f32_16x16x32_bf16(
                    af[mi], bfr[ni], acc[mi][ni], 0, 0, 0);
    }

    u16*   Cb = (u16*)Cv;
    float* Cf = (float*)Cv;
    #pragma unroll
    for (int mi = 0; mi < WM; mi++) {
        #pragma unroll
        for (int r = 0; r < 4; r++) {
            int grow = rowBase + wr * WM * 16 + mi * 16 + q * 4 + r;
            #pragma unroll
            for (int ni = 0; ni < WN; ni++) {
                int gcol = colBase + wc * WN * 16 + ni * 16 + n16;
                float v = acc[mi][ni][r];
                if (EPI == 1) {
                    v += bias[grow];                   // bias over hd rows
                    int b = gcol >> 10, nn = gcol & 1023;
                    Cb[(((long)(b * 2048 + grow)) << 10) + nn] = f2bf(v);
                } else {
                    v += bias[gcol] + resid[(long)grow * 256 + gcol];
                    Cf[(long)grow * 256 + gcol] = 1.f / (1.f + __expf(-v));
                }
            }
        }
    }
}

// -------- fused attention: out_h = softmax(adj*exp(leaky(q+k))) @ V --------
// One block = 64 query rows x all 256 d-cols for one (b,h). P-tile generated
// in LDS (bf16) on the fly from the adj BITMASK (not fp32 adj); row-sums
// accumulated in registers; scaled 1/l at epilogue. P never hits HBM.
// NOTE: no min-waves clamp — round-2's __launch_bounds__(256,2) caused the
// allocator to pick 64 arch VGPRs and spill ~500 MB of scratch per dispatch.
__global__ __launch_bounds__(256)
void k_attn(const u32* __restrict__ maskW, const float* __restrict__ qv,
            const float* __restrict__ kv, const u16* __restrict__ fpjT,
            u16* __restrict__ outh) {
    __shared__ u16 As[64 * 40];           // P-tile 64 x 32
    __shared__ u16 Bs[256 * 40];          // V^T tile 256(d) x 32(j)
    __shared__ float qS[64], kS[1024], lsumS[256], rlS[64];

    int z = blockIdx.y;                   // bh
    int b = z >> 3, h = z & 7;
    int i0 = blockIdx.x * 64;
    int tid = threadIdx.x;
    int wave = tid >> 6, lane = tid & 63;
    int wr = wave >> 1, wc = wave & 1;
    int q  = lane >> 4, n16 = lane & 15;

    *(float4*)&kS[tid * 4] = *(const float4*)&kv[(z << 10) + tid * 4];
    if (tid < 64) qS[tid] = qv[(z << 10) + i0 + tid];
    __syncthreads();

    floatx4 acc[2][8] = {};
    int sm = tid >> 2;                    // V staging row
    int sk = (tid & 3) * 8;
    int ar = tid >> 2;                    // P row (0..63)
    int jq = (tid & 3) * 8;               // P j-offset within BK
    // 32 u32 mask words per (b,row); word w covers cols [32w, 32w+32)
    const u32* mrow = maskW + (((long)(b << 10) + i0 + ar) << 5);
    const u16* Vbase = fpjT + ((long)z << 18);
    float lsum = 0.f;

    for (int k0 = 0; k0 < 1024; k0 += 32) {
        int4 bl[4];
        #pragma unroll
        for (int r = 0; r < 4; r++)
            bl[r] = *(const int4*)&Vbase[(long)(sm + 64 * r) * 1024 + k0 + sk];
        u32 mw = mrow[k0 >> 5] >> jq;     // 8 mask bits for this thread
        float qi = qS[ar];
        short8 pv;
        #pragma unroll
        for (int e = 0; e < 8; e++) {
            float s = qi + kS[k0 + jq + e];
            s = s > 0.f ? s : 0.01f * s;             // leaky_relu
            float p = ((mw >> e) & 1u) ? __expf(s) : 0.f;
            lsum += p;
            pv[e] = (short)f2bf(p);
        }
        __syncthreads();   // previous iter's frag reads done
        *(short8*)&As[ar * 40 + jq] = pv;
        #pragma unroll
        for (int r = 0; r < 4; r++)
            *(int4*)&Bs[(sm + 64 * r) * 40 + sk] = bl[r];
        __syncthreads();
        short8 af[2], bfr[8];
        #pragma unroll
        for (int i = 0; i < 2; i++)
            af[i] = *(short8*)&As[(wr * 32 + i * 16 + n16) * 40 + q * 8];
        #pragma unroll
        for (int i = 0; i < 8; i++)
            bfr[i] = *(short8*)&Bs[(wc * 128 + i * 16 + n16) * 40 + q * 8];
        #pragma unroll
        for (int mi = 0; mi < 2; mi++)
            #pragma unroll
            for (int ni = 0; ni < 8; ni++)
                acc[mi][ni] = __builtin_amdgcn_mfma_f32_16x16x32_bf16(
                    af[mi], bfr[ni], acc[mi][ni], 0, 0, 0);
    }

    // row-sum reduction: 4 threads per row
    lsumS[tid] = lsum;
    __syncthreads();
    if (tid < 64) {
        float l = lsumS[4 * tid] + lsumS[4 * tid + 1] +
                  lsumS[4 * tid + 2] + lsumS[4 * tid + 3];
        rlS[tid] = l > 0.f ? 1.f / l : 0.f;
    }
    __syncthreads();

    #pragma unroll
    for (int mi = 0; mi < 2; mi++) {
        #pragma unroll
        for (int r = 0; r < 4; r++) {
            int grow = wr * 32 + mi * 16 + q * 4 + r;
            float s = rlS[grow];
            long base = (long)(b * 1024 + i0 + grow) * 2048 + h * 256;
            #pragma unroll
            for (int ni = 0; ni < 8; ni++) {
                int gcol = wc * 128 + ni * 16 + n16;
                outh[base + gcol] = f2bf(acc[mi][ni][r] * s);
            }
        }
    }
}

extern "C" void kernel_launch(void* const* d_in, const int* in_sizes, int n_in,
                              void* d_out, int out_size, void* d_ws, size_t ws_size,
                              hipStream_t stream) {
    const float* feats = (const float*)d_in[0];
    const float* adj   = (const float*)d_in[1];
    const float* fc_w  = (const float*)d_in[2];
    const float* fc_b  = (const float*)d_in[3];
    const float* q_w   = (const float*)d_in[4];
    const float* q_b   = (const float*)d_in[5];
    const float* k_w   = (const float*)d_in[6];
    const float* k_b   = (const float*)d_in[7];
    const float* fp_w  = (const float*)d_in[8];
    const float* fp_b  = (const float*)d_in[9];

    char* ws = (char*)d_ws;
    u16*   featsB = (u16*)ws;   ws += (size_t)2097152 * 2;   // [8192][256] bf16
    u16*   fcwT   = (u16*)ws;   ws += (size_t)524288 * 2;    // [2048][256] bf16
    u16*   fpwT   = (u16*)ws;   ws += (size_t)524288 * 2;    // [256][2048] bf16
    u16*   fpjT   = (u16*)ws;   ws += (size_t)16777216 * 2;  // [b,hd,n] bf16
    float* qv     = (float*)ws; ws += (size_t)65536 * 4;     // [b,h,n]
    float* kv     = (float*)ws; ws += (size_t)65536 * 4;
    u16*   outh   = (u16*)ws;   ws += (size_t)16777216 * 2;  // [(b,n)][(h,d)] bf16
    u64*   maskB  = (u64*)ws;   ws += (size_t)131072 * 8;    // adj bits, 1 MB

    // setup: conversions, bitmask, weight transposes
    k_cvt<<<2048, 256, 0, stream>>>(feats, featsB);
    k_mask<<<32768, 256, 0, stream>>>(adj, maskB);
    k_transpose<<<dim3(32, 4), 256, 0, stream>>>(fc_w, fcwT, 256, 2048);
    k_transpose<<<dim3(4, 32), 256, 0, stream>>>(fp_w, fpwT, 2048, 256);

    // G1 (swapped orientation): fpjT[hd][n] = fc_w^T @ feats^T, coalesced store
    gemm_nt<1, 128, 128, 4, 4><<<dim3(64, 16), 256, 0, stream>>>(
        fcwT, featsB, 256, 256, 256, (void*)fpjT, fc_b, nullptr);

    // q, k
    k_qk<<<dim3(4, 64), 256, 0, stream>>>(fpjT, q_w, k_w, q_b, k_b, qv, kv);

    // fused scores + P@V + 1/l scaling
    k_attn<<<dim3(16, 64), 256, 0, stream>>>((const u32*)maskB, qv, kv, fpjT, outh);

    // G3: sigmoid(outh @ fp_w + fp_b + feats), 64x64 tiles -> 512 blocks
    gemm_nt<3, 64, 64, 2, 2><<<dim3(4, 128), 256, 0, stream>>>(
        outh, fpwT, 2048, 2048, 2048, d_out, fp_b, feats);
}

// Round 4
// 302.602 us; speedup vs baseline: 1.3855x; 1.2457x over previous
//
#include <hip/hip_runtime.h>
#include <hip/hip_bf16.h>

typedef unsigned short u16;
typedef unsigned int u32;
typedef unsigned long long u64;
typedef __attribute__((ext_vector_type(8))) short short8;   // 8 bf16 = 4 VGPR (MFMA A/B frag)
typedef __attribute__((ext_vector_type(4))) float floatx4;  // MFMA C/D frag
typedef const __attribute__((address_space(1))) void* gp_t; // global ptr for DMA
typedef __attribute__((address_space(3))) void* sp_t;       // LDS ptr for DMA

static __device__ __forceinline__ u16 f2bf(float x) {
    __hip_bfloat16 h = __float2bfloat16(x);
    union { __hip_bfloat16 h; u16 u; } cv; cv.h = h; return cv.u;
}
static __device__ __forceinline__ float bf2f(u16 u) {
    union { u16 u; __hip_bfloat16 h; } cv; cv.u = u;
    return __bfloat162float(cv.h);
}
static __device__ __forceinline__ u32 pk2bf(float a, float b) {
    return (u32)f2bf(a) | ((u32)f2bf(b) << 16);
}

// ---------------- elementwise fp32 -> bf16 convert (feats) ----------------
__global__ void k_cvt(const float* __restrict__ in, u16* __restrict__ out) {
    int i = (blockIdx.x * 256 + threadIdx.x) * 4;
    float4 v = *(const float4*)&in[i];
    out[i + 0] = f2bf(v.x); out[i + 1] = f2bf(v.y);
    out[i + 2] = f2bf(v.z); out[i + 3] = f2bf(v.w);
}

// ---------------- adj fp32 -> bitmask (1 bit per entry, wave ballot) --------
__global__ void k_mask(const float* __restrict__ adj, u64* __restrict__ m) {
    long i = (long)blockIdx.x * 256 + threadIdx.x;
    float v = adj[i];
    u64 bm = __ballot(v > 0.f);
    if ((threadIdx.x & 63) == 0) m[i >> 6] = bm;
}

// ---------- tiled transpose fp32[R][C] -> bf16[C][R] (weight prep) ----------
__global__ void k_transpose(const float* __restrict__ in, u16* __restrict__ out,
                            int R, int Cn) {
    __shared__ float t[64][65];
    int c  = threadIdx.x & 63;
    int r0 = threadIdx.x >> 6;
    int bx = blockIdx.x, by = blockIdx.y;
    for (int rr = r0; rr < 64; rr += 4)
        t[rr][c] = in[(long)(by * 64 + rr) * Cn + bx * 64 + c];
    __syncthreads();
    for (int rr = r0; rr < 64; rr += 4)
        out[(long)(bx * 64 + rr) * R + by * 64 + c] = f2bf(t[c][rr]);
}

// ---------------- q/k projections from fpjT[b,hd,n] ----------------
__global__ void k_qk(const u16* __restrict__ fpjT,
                     const float* __restrict__ qw, const float* __restrict__ kw,
                     const float* __restrict__ qb, const float* __restrict__ kb,
                     float* __restrict__ qo, float* __restrict__ ko) {
    int bh = blockIdx.y;
    int n  = blockIdx.x * 256 + threadIdx.x;
    __shared__ float wq[256], wk[256];
    wq[threadIdx.x] = qw[threadIdx.x];
    wk[threadIdx.x] = kw[threadIdx.x];
    __syncthreads();
    const u16* base = fpjT + ((long)bh << 18) + n;
    float qa = 0.f, ka = 0.f;
    for (int d = 0; d < 256; d++) {
        float v = bf2f(base[(long)d << 10]);         // coalesced over n
        qa += v * wq[d]; ka += v * wk[d];
    }
    qo[(bh << 10) + n] = qa + qb[0];
    ko[(bh << 10) + n] = ka + kb[0];
}

// ---------------- templated NT bf16 GEMM: C = A[M][K] * Bt[N][K]^T -----------
template <int EPI, int BM, int BN, int WM, int WN>
__global__ __launch_bounds__(256, 2)
void gemm_nt(const u16* __restrict__ A, const u16* __restrict__ Bt,
             int lda, int ldb, int K,
             void* __restrict__ Cv,
             const float* __restrict__ bias,
             const float* __restrict__ resid) {
    __shared__ u16 As[BM * 40];
    __shared__ u16 Bs[BN * 40];
    int rowBase = blockIdx.y * BM;
    int colBase = blockIdx.x * BN;
    int tid  = threadIdx.x;
    int wave = tid >> 6, lane = tid & 63;
    int wr = wave >> 1, wc = wave & 1;
    int q  = lane >> 4, n16 = lane & 15;

    floatx4 acc[WM][WN] = {};

    int sm = tid >> 2;          // 0..63 staging row
    int sk = (tid & 3) * 8;     // k-chunk within BK=32

    for (int k0 = 0; k0 < K; k0 += 32) {
        int4 al[BM / 64], bl[BN / 64];
        #pragma unroll
        for (int r = 0; r < BM / 64; r++)
            al[r] = *(const int4*)&A[(long)(rowBase + sm + 64 * r) * lda + k0 + sk];
        #pragma unroll
        for (int r = 0; r < BN / 64; r++)
            bl[r] = *(const int4*)&Bt[(long)(colBase + sm + 64 * r) * ldb + k0 + sk];
        __syncthreads();   // previous iter's frag reads done
        #pragma unroll
        for (int r = 0; r < BM / 64; r++)
            *(int4*)&As[(sm + 64 * r) * 40 + sk] = al[r];
        #pragma unroll
        for (int r = 0; r < BN / 64; r++)
            *(int4*)&Bs[(sm + 64 * r) * 40 + sk] = bl[r];
        __syncthreads();
        short8 af[WM], bfr[WN];
        #pragma unroll
        for (int i = 0; i < WM; i++)
            af[i] = *(short8*)&As[(wr * WM * 16 + i * 16 + n16) * 40 + q * 8];
        #pragma unroll
        for (int i = 0; i < WN; i++)
            bfr[i] = *(short8*)&Bs[(wc * WN * 16 + i * 16 + n16) * 40 + q * 8];
        #pragma unroll
        for (int mi = 0; mi < WM; mi++)
            #pragma unroll
            for (int ni = 0; ni < WN; ni++)
                acc[mi][ni] = __builtin_amdgcn_mfma_f32_16x16x32_bf16(
                    af[mi], bfr[ni], acc[mi][ni], 0, 0, 0);
    }

    u16*   Cb = (u16*)Cv;
    float* Cf = (float*)Cv;
    #pragma unroll
    for (int mi = 0; mi < WM; mi++) {
        #pragma unroll
        for (int r = 0; r < 4; r++) {
            int grow = rowBase + wr * WM * 16 + mi * 16 + q * 4 + r;
            #pragma unroll
            for (int ni = 0; ni < WN; ni++) {
                int gcol = colBase + wc * WN * 16 + ni * 16 + n16;
                float v = acc[mi][ni][r];
                if (EPI == 1) {
                    v += bias[grow];                   // bias over hd rows
                    int b = gcol >> 10, nn = gcol & 1023;
                    Cb[(((long)(b * 2048 + grow)) << 10) + nn] = f2bf(v);
                } else {
                    v += bias[gcol] + resid[(long)grow * 256 + gcol];
                    Cf[(long)grow * 256 + gcol] = 1.f / (1.f + __expf(-v));
                }
            }
        }
    }
}

// -------- fused attention: out_h = softmax(adj*exp(leaky(q+k))) @ V --------
// V staged via global_load_lds DMA (no staging VGPRs -> nothing to spill);
// P-tile packed through named u32 scalars. Bs unpadded (DMA requires
// base + lane*16 contiguous layout). amdgpu_waves_per_eu(2) widens the
// allocator's register budget (rounds 2-3: it capped at 64-76 VGPRs and
// spilled ~350-540 MB of scratch per dispatch).
__global__ __launch_bounds__(256)
__attribute__((amdgpu_waves_per_eu(2)))
void k_attn(const u32* __restrict__ maskW, const float* __restrict__ qv,
            const float* __restrict__ kv, const u16* __restrict__ fpjT,
            u16* __restrict__ outh) {
    __shared__ u16 As[64 * 40];           // P-tile 64 x 32, padded (stride 40)
    __shared__ u16 Bs[256 * 32];          // V^T tile 256(d) x 32(j), DMA target
    __shared__ float qS[64], kS[1024], lsumS[256], rlS[64];

    int z = blockIdx.y;                   // bh
    int b = z >> 3, h = z & 7;
    int i0 = blockIdx.x * 64;
    int tid = threadIdx.x;
    int wave = tid >> 6, lane = tid & 63;
    int wr = wave >> 1, wc = wave & 1;
    int q  = lane >> 4, n16 = lane & 15;

    *(float4*)&kS[tid * 4] = *(const float4*)&kv[(z << 10) + tid * 4];
    if (tid < 64) qS[tid] = qv[(z << 10) + i0 + tid];
    __syncthreads();

    floatx4 acc[2][8] = {};
    int ar = tid >> 2;                    // P row (0..63)
    int jq = (tid & 3) * 8;               // P j-offset within BK
    const u32* mrow = maskW + (((long)(b << 10) + i0 + ar) << 5);
    const u16* Vbase = fpjT + ((long)z << 18);
    // DMA: wave w covers Bs rows w*64..w*64+63; inst t covers 16 rows;
    // lane slot = row (lane>>2), 16-B chunk (lane&3)  ->  base + lane*16.
    int vrow = wave * 64 + (lane >> 2);
    int vchk = (lane & 3) * 8;
    float lsum = 0.f;

    for (int k0 = 0; k0 < 1024; k0 += 32) {
        // ---- P-tile compute, registers only ----
        u32 mw = mrow[k0 >> 5] >> jq;
        float qi = qS[ar];
        float4 kA = *(const float4*)&kS[k0 + jq];
        float4 kB = *(const float4*)&kS[k0 + jq + 4];
        float kk[8] = {kA.x, kA.y, kA.z, kA.w, kB.x, kB.y, kB.z, kB.w};
        float pe[8];
        #pragma unroll
        for (int e = 0; e < 8; e++) {
            float s = qi + kk[e];
            s = s > 0.f ? s : 0.01f * s;             // leaky_relu
            float p = ((mw >> e) & 1u) ? __expf(s) : 0.f;
            lsum += p;
            pe[e] = p;
        }
        u32 w0 = pk2bf(pe[0], pe[1]);
        u32 w1 = pk2bf(pe[2], pe[3]);
        u32 w2 = pk2bf(pe[4], pe[5]);
        u32 w3 = pk2bf(pe[6], pe[7]);

        __syncthreads();   // previous iter's frag reads done
        // ---- V staging: async DMA straight into Bs ----
        #pragma unroll
        for (int t = 0; t < 4; t++)
            __builtin_amdgcn_global_load_lds(
                (gp_t)&Vbase[(long)(vrow + t * 16) * 1024 + k0 + vchk],
                (sp_t)&Bs[(wave * 64 + t * 16) * 32],
                16, 0, 0);
        // ---- P-tile store ----
        int4 pw = make_int4((int)w0, (int)w1, (int)w2, (int)w3);
        *(int4*)&As[ar * 40 + jq] = pw;
        __syncthreads();   // As visible + DMA drained (vmcnt before barrier)

        short8 af[2], bfr[8];
        #pragma unroll
        for (int i = 0; i < 2; i++)
            af[i] = *(short8*)&As[(wr * 32 + i * 16 + n16) * 40 + q * 8];
        #pragma unroll
        for (int i = 0; i < 8; i++)
            bfr[i] = *(short8*)&Bs[(wc * 128 + i * 16 + n16) * 32 + q * 8];
        #pragma unroll
        for (int mi = 0; mi < 2; mi++)
            #pragma unroll
            for (int ni = 0; ni < 8; ni++)
                acc[mi][ni] = __builtin_amdgcn_mfma_f32_16x16x32_bf16(
                    af[mi], bfr[ni], acc[mi][ni], 0, 0, 0);
    }

    // row-sum reduction: 4 threads per row
    lsumS[tid] = lsum;
    __syncthreads();
    if (tid < 64) {
        float l = lsumS[4 * tid] + lsumS[4 * tid + 1] +
                  lsumS[4 * tid + 2] + lsumS[4 * tid + 3];
        rlS[tid] = l > 0.f ? 1.f / l : 0.f;
    }
    __syncthreads();

    #pragma unroll
    for (int mi = 0; mi < 2; mi++) {
        #pragma unroll
        for (int r = 0; r < 4; r++) {
            int grow = wr * 32 + mi * 16 + q * 4 + r;
            float s = rlS[grow];
            long base = (long)(b * 1024 + i0 + grow) * 2048 + h * 256;
            #pragma unroll
            for (int ni = 0; ni < 8; ni++) {
                int gcol = wc * 128 + ni * 16 + n16;
                outh[base + gcol] = f2bf(acc[mi][ni][r] * s);
            }
        }
    }
}

extern "C" void kernel_launch(void* const* d_in, const int* in_sizes, int n_in,
                              void* d_out, int out_size, void* d_ws, size_t ws_size,
                              hipStream_t stream) {
    const float* feats = (const float*)d_in[0];
    const float* adj   = (const float*)d_in[1];
    const float* fc_w  = (const float*)d_in[2];
    const float* fc_b  = (const float*)d_in[3];
    const float* q_w   = (const float*)d_in[4];
    const float* q_b   = (const float*)d_in[5];
    const float* k_w   = (const float*)d_in[6];
    const float* k_b   = (const float*)d_in[7];
    const float* fp_w  = (const float*)d_in[8];
    const float* fp_b  = (const float*)d_in[9];

    char* ws = (char*)d_ws;
    u16*   featsB = (u16*)ws;   ws += (size_t)2097152 * 2;   // [8192][256] bf16
    u16*   fcwT   = (u16*)ws;   ws += (size_t)524288 * 2;    // [2048][256] bf16
    u16*   fpwT   = (u16*)ws;   ws += (size_t)524288 * 2;    // [256][2048] bf16
    u16*   fpjT   = (u16*)ws;   ws += (size_t)16777216 * 2;  // [b,hd,n] bf16
    float* qv     = (float*)ws; ws += (size_t)65536 * 4;     // [b,h,n]
    float* kv     = (float*)ws; ws += (size_t)65536 * 4;
    u16*   outh   = (u16*)ws;   ws += (size_t)16777216 * 2;  // [(b,n)][(h,d)] bf16
    u64*   maskB  = (u64*)ws;   ws += (size_t)131072 * 8;    // adj bits, 1 MB

    // setup: conversions, bitmask, weight transposes
    k_cvt<<<2048, 256, 0, stream>>>(feats, featsB);
    k_mask<<<32768, 256, 0, stream>>>(adj, maskB);
    k_transpose<<<dim3(32, 4), 256, 0, stream>>>(fc_w, fcwT, 256, 2048);
    k_transpose<<<dim3(4, 32), 256, 0, stream>>>(fp_w, fpwT, 2048, 256);

    // G1 (swapped orientation): fpjT[hd][n] = fc_w^T @ feats^T, coalesced store
    gemm_nt<1, 128, 128, 4, 4><<<dim3(64, 16), 256, 0, stream>>>(
        fcwT, featsB, 256, 256, 256, (void*)fpjT, fc_b, nullptr);

    // q, k
    k_qk<<<dim3(4, 64), 256, 0, stream>>>(fpjT, q_w, k_w, q_b, k_b, qv, kv);

    // fused scores + P@V + 1/l scaling
    k_attn<<<dim3(16, 64), 256, 0, stream>>>((const u32*)maskB, qv, kv, fpjT, outh);

    // G3: sigmoid(outh @ fp_w + fp_b + feats), 64x64 tiles -> 512 blocks
    gemm_nt<3, 64, 64, 2, 2><<<dim3(4, 128), 256, 0, stream>>>(
        outh, fpwT, 2048, 2048, 2048, d_out, fp_b, feats);
}

// Round 5
// 300.824 us; speedup vs baseline: 1.3937x; 1.0059x over previous
//
#include <hip/hip_runtime.h>
#include <hip/hip_bf16.h>

typedef unsigned short u16;
typedef unsigned int u32;
typedef unsigned long long u64;
typedef __attribute__((ext_vector_type(8))) short short8;   // 8 bf16 = 4 VGPR (MFMA A/B frag)
typedef __attribute__((ext_vector_type(4))) float floatx4;  // MFMA C/D frag
typedef const __attribute__((address_space(1))) void* gp_t; // global ptr for DMA
typedef __attribute__((address_space(3))) void* sp_t;       // LDS ptr for DMA

static __device__ __forceinline__ u16 f2bf(float x) {
    __hip_bfloat16 h = __float2bfloat16(x);
    union { __hip_bfloat16 h; u16 u; } cv; cv.h = h; return cv.u;
}
static __device__ __forceinline__ float bf2f(u16 u) {
    union { u16 u; __hip_bfloat16 h; } cv; cv.u = u;
    return __bfloat162float(cv.h);
}
static __device__ __forceinline__ u32 pk2bf(float a, float b) {
    return (u32)f2bf(a) | ((u32)f2bf(b) << 16);
}

// ---------------- elementwise fp32 -> bf16 convert (feats) ----------------
__global__ void k_cvt(const float* __restrict__ in, u16* __restrict__ out) {
    int i = (blockIdx.x * 256 + threadIdx.x) * 4;
    float4 v = *(const float4*)&in[i];
    out[i + 0] = f2bf(v.x); out[i + 1] = f2bf(v.y);
    out[i + 2] = f2bf(v.z); out[i + 3] = f2bf(v.w);
}

// ---------------- adj fp32 -> bitmask (1 bit per entry, wave ballot) --------
__global__ void k_mask(const float* __restrict__ adj, u64* __restrict__ m) {
    long i = (long)blockIdx.x * 256 + threadIdx.x;
    float v = adj[i];
    u64 bm = __ballot(v > 0.f);
    if ((threadIdx.x & 63) == 0) m[i >> 6] = bm;
}

// ---------- tiled transpose fp32[R][C] -> bf16[C][R] (weight prep) ----------
__global__ void k_transpose(const float* __restrict__ in, u16* __restrict__ out,
                            int R, int Cn) {
    __shared__ float t[64][65];
    int c  = threadIdx.x & 63;
    int r0 = threadIdx.x >> 6;
    int bx = blockIdx.x, by = blockIdx.y;
    for (int rr = r0; rr < 64; rr += 4)
        t[rr][c] = in[(long)(by * 64 + rr) * Cn + bx * 64 + c];
    __syncthreads();
    for (int rr = r0; rr < 64; rr += 4)
        out[(long)(bx * 64 + rr) * R + by * 64 + c] = f2bf(t[c][rr]);
}

// ---- effective q/k weights: Wq[d,h] = fc_w[d, h*256:+256] @ q_w, + consts ----
// blockIdx = kind*8 + h (kind 0=q, 1=k); thread = d.
__global__ void k_wqk(const float* __restrict__ fc_w, const float* __restrict__ fc_b,
                      const float* __restrict__ q_w, const float* __restrict__ q_b,
                      const float* __restrict__ k_w, const float* __restrict__ k_b,
                      float* __restrict__ W, float* __restrict__ C) {
    int h = blockIdx.x & 7, kind = blockIdx.x >> 3;
    int d = threadIdx.x;
    const float* w = kind ? k_w : q_w;
    __shared__ float ws_[256];
    ws_[d] = w[d];
    __syncthreads();
    const float* row = fc_w + (long)d * 2048 + h * 256;
    float a = 0.f;
    for (int i = 0; i < 256; i++) a += row[i] * ws_[i];
    W[(long)blockIdx.x * 256 + d] = a;
    if (d == 0) {
        float cb = 0.f;
        const float* fb = fc_b + h * 256;
        for (int i = 0; i < 256; i++) cb += fb[i] * ws_[i];
        C[blockIdx.x] = cb + (kind ? k_b[0] : q_b[0]);
    }
}

// ---- q/k: [8192 rows] x [16 eff-weight cols], K=256, from bf16 feats ----
__global__ void k_qk2(const u16* __restrict__ featsB, const float* __restrict__ W,
                      const float* __restrict__ C,
                      float* __restrict__ qo, float* __restrict__ ko) {
    __shared__ float Wl[16][256];
    int tid = threadIdx.x;
    for (int i = tid; i < 16 * 256; i += 256)
        ((float*)Wl)[i] = W[i];
    __syncthreads();
    int n = blockIdx.x * 256 + tid;
    const u16* row = featsB + (long)n * 256;
    float qa[8] = {}, ka[8] = {};
    for (int d0 = 0; d0 < 256; d0 += 8) {
        short8 v8 = *(const short8*)&row[d0];
        #pragma unroll
        for (int e = 0; e < 8; e++) {
            float v = bf2f((u16)v8[e]);
            #pragma unroll
            for (int h = 0; h < 8; h++) {
                qa[h] += v * Wl[h][d0 + e];
                ka[h] += v * Wl[8 + h][d0 + e];
            }
        }
    }
    int b = n >> 10, nn = n & 1023;
    #pragma unroll
    for (int h = 0; h < 8; h++) {
        qo[((b * 8 + h) << 10) + nn] = qa[h] + C[h];
        ko[((b * 8 + h) << 10) + nn] = ka[h] + C[8 + h];
    }
}

// ---------------- templated NT bf16 GEMM: C = A[M][K] * Bt[N][K]^T -----------
template <int EPI, int BM, int BN, int WM, int WN>
__global__ __launch_bounds__(256, 2)
void gemm_nt(const u16* __restrict__ A, const u16* __restrict__ Bt,
             int lda, int ldb, int K,
             void* __restrict__ Cv,
             const float* __restrict__ bias,
             const float* __restrict__ resid) {
    __shared__ u16 As[BM * 40];
    __shared__ u16 Bs[BN * 40];
    int rowBase = blockIdx.y * BM;
    int colBase = blockIdx.x * BN;
    int tid  = threadIdx.x;
    int wave = tid >> 6, lane = tid & 63;
    int wr = wave >> 1, wc = wave & 1;
    int q  = lane >> 4, n16 = lane & 15;

    floatx4 acc[WM][WN] = {};

    int sm = tid >> 2;          // 0..63 staging row
    int sk = (tid & 3) * 8;     // k-chunk within BK=32

    for (int k0 = 0; k0 < K; k0 += 32) {
        int4 al[BM / 64], bl[BN / 64];
        #pragma unroll
        for (int r = 0; r < BM / 64; r++)
            al[r] = *(const int4*)&A[(long)(rowBase + sm + 64 * r) * lda + k0 + sk];
        #pragma unroll
        for (int r = 0; r < BN / 64; r++)
            bl[r] = *(const int4*)&Bt[(long)(colBase + sm + 64 * r) * ldb + k0 + sk];
        __syncthreads();   // previous iter's frag reads done
        #pragma unroll
        for (int r = 0; r < BM / 64; r++)
            *(int4*)&As[(sm + 64 * r) * 40 + sk] = al[r];
        #pragma unroll
        for (int r = 0; r < BN / 64; r++)
            *(int4*)&Bs[(sm + 64 * r) * 40 + sk] = bl[r];
        __syncthreads();
        short8 af[WM], bfr[WN];
        #pragma unroll
        for (int i = 0; i < WM; i++)
            af[i] = *(short8*)&As[(wr * WM * 16 + i * 16 + n16) * 40 + q * 8];
        #pragma unroll
        for (int i = 0; i < WN; i++)
            bfr[i] = *(short8*)&Bs[(wc * WN * 16 + i * 16 + n16) * 40 + q * 8];
        #pragma unroll
        for (int mi = 0; mi < WM; mi++)
            #pragma unroll
            for (int ni = 0; ni < WN; ni++)
                acc[mi][ni] = __builtin_amdgcn_mfma_f32_16x16x32_bf16(
                    af[mi], bfr[ni], acc[mi][ni], 0, 0, 0);
    }

    u16*   Cb = (u16*)Cv;
    float* Cf = (float*)Cv;
    #pragma unroll
    for (int mi = 0; mi < WM; mi++) {
        #pragma unroll
        for (int r = 0; r < 4; r++) {
            int grow = rowBase + wr * WM * 16 + mi * 16 + q * 4 + r;
            #pragma unroll
            for (int ni = 0; ni < WN; ni++) {
                int gcol = colBase + wc * WN * 16 + ni * 16 + n16;
                float v = acc[mi][ni][r];
                if (EPI == 1) {
                    v += bias[grow];                   // bias over hd rows
                    int b = gcol >> 10, nn = gcol & 1023;
                    Cb[(((long)(b * 2048 + grow)) << 10) + nn] = f2bf(v);
                } else {
                    v += bias[gcol] + resid[(long)grow * 256 + gcol];
                    Cf[(long)grow * 256 + gcol] = 1.f / (1.f + __expf(-v));
                }
            }
        }
    }
}

// -------- fused attention v3: out_h = softmax(adj*exp(leaky(q+k))) @ V --------
// BM=128 rows x full d=256 per block; grid 512 = 2 blocks/CU.
// Double-buffered As (P-tile) + Bs (V-tile via global_load_lds DMA), ONE
// barrier per K-iter: frag-reads(p) -> DMA(k+1 -> p^1) -> P-compute(k+1 -> p^1)
// -> MFMA(p) -> barrier. The vmcnt(0) drain at the barrier lands after the
// MFMA+VALU phase, so the DMA is overlapped instead of serializing.
__global__ __launch_bounds__(256)
__attribute__((amdgpu_waves_per_eu(2)))
void k_attn(const u32* __restrict__ maskW, const float* __restrict__ qv,
            const float* __restrict__ kv, const u16* __restrict__ fpjT,
            u16* __restrict__ outh) {
    __shared__ u16 As[2][128 * 40];       // P-tiles 128 x 32, stride 40
    __shared__ u16 Bs[2][256 * 32];       // V^T tiles 256(d) x 32(j), DMA target
    __shared__ float qS[128], kS[1024], lsumS[256], rlS[128];

    int z = blockIdx.y;                   // bh
    int b = z >> 3, h = z & 7;
    int i0 = blockIdx.x * 128;
    int tid = threadIdx.x;
    int wave = tid >> 6, lane = tid & 63;
    int wr = wave >> 1, wc = wave & 1;
    int q  = lane >> 4, n16 = lane & 15;

    *(float4*)&kS[tid * 4] = *(const float4*)&kv[(z << 10) + tid * 4];
    if (tid < 128) qS[tid] = qv[(z << 10) + i0 + tid];

    floatx4 acc[4][8] = {};
    int ar = tid >> 1;                    // P row (0..127)
    int jq = (tid & 1) * 16;              // P j-offset within BK (16 elems each)
    const u32* mrow = maskW + (((long)(b << 10) + i0 + ar) << 5);
    const u16* Vbase = fpjT + ((long)z << 18);
    int vrow = wave * 64 + (lane >> 2);   // DMA: wave covers 64 V rows
    int vchk = (lane & 3) * 8;
    float lsum = 0.f;

    auto dma_v = [&](int k0, int p) {
        #pragma unroll
        for (int t = 0; t < 4; t++)
            __builtin_amdgcn_global_load_lds(
                (gp_t)&Vbase[(long)(vrow + t * 16) * 1024 + k0 + vchk],
                (sp_t)&Bs[p][(wave * 64 + t * 16) * 32],
                16, 0, 0);
    };
    auto stage_p = [&](int k0, int p) {
        u32 mw = mrow[k0 >> 5] >> jq;     // 16 mask bits for this thread
        float qi = qS[ar];
        float lkk[16];
        *(float4*)&lkk[0]  = *(const float4*)&kS[k0 + jq + 0];
        *(float4*)&lkk[4]  = *(const float4*)&kS[k0 + jq + 4];
        *(float4*)&lkk[8]  = *(const float4*)&kS[k0 + jq + 8];
        *(float4*)&lkk[12] = *(const float4*)&kS[k0 + jq + 12];
        u32 pw[8];
        #pragma unroll
        for (int e2 = 0; e2 < 8; e2++) {
            float s0 = qi + lkk[2 * e2];
            s0 = s0 > 0.f ? s0 : 0.01f * s0;
            float p0 = ((mw >> (2 * e2)) & 1u) ? __expf(s0) : 0.f;
            float s1 = qi + lkk[2 * e2 + 1];
            s1 = s1 > 0.f ? s1 : 0.01f * s1;
            float p1 = ((mw >> (2 * e2 + 1)) & 1u) ? __expf(s1) : 0.f;
            lsum += p0 + p1;
            pw[e2] = pk2bf(p0, p1);
        }
        *(int4*)&As[p][ar * 40 + jq]     = *(int4*)&pw[0];
        *(int4*)&As[p][ar * 40 + jq + 8] = *(int4*)&pw[4];
    };

    __syncthreads();                      // qS/kS visible
    dma_v(0, 0);
    stage_p(0, 0);
    __syncthreads();                      // iter 0 staged (DMA drained here)

    for (int k0 = 0; k0 < 1024; k0 += 32) {
        int p = (k0 >> 5) & 1;
        short8 af[4], bfr[8];
        #pragma unroll
        for (int i = 0; i < 4; i++)
            af[i] = *(short8*)&As[p][(wr * 64 + i * 16 + n16) * 40 + q * 8];
        #pragma unroll
        for (int i = 0; i < 8; i++)
            bfr[i] = *(short8*)&Bs[p][(wc * 128 + i * 16 + n16) * 32 + q * 8];
        if (k0 + 32 < 1024) {
            dma_v(k0 + 32, p ^ 1);
            stage_p(k0 + 32, p ^ 1);
        }
        #pragma unroll
        for (int mi = 0; mi < 4; mi++)
            #pragma unroll
            for (int ni = 0; ni < 8; ni++)
                acc[mi][ni] = __builtin_amdgcn_mfma_f32_16x16x32_bf16(
                    af[mi], bfr[ni], acc[mi][ni], 0, 0, 0);
        __syncthreads();                  // next buffer staged + DMA drained
    }

    // row-sum: 2 threads per row
    lsumS[tid] = lsum;
    __syncthreads();
    if (tid < 128) {
        float l = lsumS[2 * tid] + lsumS[2 * tid + 1];
        rlS[tid] = l > 0.f ? 1.f / l : 0.f;
    }
    __syncthreads();

    #pragma unroll
    for (int mi = 0; mi < 4; mi++) {
        #pragma unroll
        for (int r = 0; r < 4; r++) {
            int grow = wr * 64 + mi * 16 + q * 4 + r;
            float s = rlS[grow];
            long base = (long)(b * 1024 + i0 + grow) * 2048 + h * 256;
            #pragma unroll
            for (int ni = 0; ni < 8; ni++) {
                int gcol = wc * 128 + ni * 16 + n16;
                outh[base + gcol] = f2bf(acc[mi][ni][r] * s);
            }
        }
    }
}

extern "C" void kernel_launch(void* const* d_in, const int* in_sizes, int n_in,
                              void* d_out, int out_size, void* d_ws, size_t ws_size,
                              hipStream_t stream) {
    const float* feats = (const float*)d_in[0];
    const float* adj   = (const float*)d_in[1];
    const float* fc_w  = (const float*)d_in[2];
    const float* fc_b  = (const float*)d_in[3];
    const float* q_w   = (const float*)d_in[4];
    const float* q_b   = (const float*)d_in[5];
    const float* k_w   = (const float*)d_in[6];
    const float* k_b   = (const float*)d_in[7];
    const float* fp_w  = (const float*)d_in[8];
    const float* fp_b  = (const float*)d_in[9];

    char* ws = (char*)d_ws;
    u16*   featsB = (u16*)ws;   ws += (size_t)2097152 * 2;   // [8192][256] bf16
    u16*   fcwT   = (u16*)ws;   ws += (size_t)524288 * 2;    // [2048][256] bf16
    u16*   fpwT   = (u16*)ws;   ws += (size_t)524288 * 2;    // [256][2048] bf16
    u16*   fpjT   = (u16*)ws;   ws += (size_t)16777216 * 2;  // [b,hd,n] bf16
    float* qv     = (float*)ws; ws += (size_t)65536 * 4;     // [b,h,n]
    float* kv     = (float*)ws; ws += (size_t)65536 * 4;
    u16*   outh   = (u16*)ws;   ws += (size_t)16777216 * 2;  // [(b,n)][(h,d)] bf16
    u64*   maskB  = (u64*)ws;   ws += (size_t)131072 * 8;    // adj bits, 1 MB
    float* Weff   = (float*)ws; ws += (size_t)4096 * 4;      // [16][256] eff q/k w
    float* Ceff   = (float*)ws; ws += (size_t)16 * 4;        // per-head consts

    // setup: conversions, bitmask, weight transposes, effective q/k weights
    k_cvt<<<2048, 256, 0, stream>>>(feats, featsB);
    k_mask<<<32768, 256, 0, stream>>>(adj, maskB);
    k_transpose<<<dim3(32, 4), 256, 0, stream>>>(fc_w, fcwT, 256, 2048);
    k_transpose<<<dim3(4, 32), 256, 0, stream>>>(fp_w, fpwT, 2048, 256);
    k_wqk<<<16, 256, 0, stream>>>(fc_w, fc_b, q_w, q_b, k_w, k_b, Weff, Ceff);

    // q, k directly from feats via effective weights
    k_qk2<<<32, 256, 0, stream>>>(featsB, Weff, Ceff, qv, kv);

    // G1 (swapped orientation): fpjT[hd][n] = fc_w^T @ feats^T, coalesced store
    gemm_nt<1, 128, 128, 4, 4><<<dim3(64, 16), 256, 0, stream>>>(
        fcwT, featsB, 256, 256, 256, (void*)fpjT, fc_b, nullptr);

    // fused scores + P@V + 1/l scaling
    k_attn<<<dim3(8, 64), 256, 0, stream>>>((const u32*)maskB, qv, kv, fpjT, outh);

    // G3: sigmoid(outh @ fp_w + fp_b + feats), 64x64 tiles -> 512 blocks
    gemm_nt<3, 64, 64, 2, 2><<<dim3(4, 128), 256, 0, stream>>>(
        outh, fpwT, 2048, 2048, 2048, d_out, fp_b, feats);
}